// Round 4
// baseline (583.798 us; speedup 1.0000x reference)
//
#include <hip/hip_runtime.h>
#include <hip/hip_bf16.h>

typedef __bf16 bf16_t;
typedef __bf16 bf16x8 __attribute__((ext_vector_type(8)));
typedef __bf16 bf16x4 __attribute__((ext_vector_type(4)));
typedef __bf16 bf16x2 __attribute__((ext_vector_type(2)));
typedef float f32x4 __attribute__((ext_vector_type(4)));
typedef float f32x2 __attribute__((ext_vector_type(2)));
typedef unsigned short u16;

#define NROWS 16384
#define KDIM  512
#define HID   256
#define ODIM  128
#define KS    8

__device__ __forceinline__ f32x4 mfma16(bf16x8 a, bf16x8 b, f32x4 c) {
  return __builtin_amdgcn_mfma_f32_16x16x32_bf16(a, b, c, 0, 0, 0);
}

__device__ __forceinline__ void dma16(const void* g, void* l) {
  __builtin_amdgcn_global_load_lds(
      (const __attribute__((address_space(1))) unsigned int*)g,
      (__attribute__((address_space(3))) unsigned int*)l, 16, 0, 0);
}

// ---------------------------------------------------------------------------
// prep: x fp32 -> xb bf16 ; W1 -> W1T bf16 ; W2 -> W2T bf16 ; zero gmax
// ---------------------------------------------------------------------------
__global__ __launch_bounds__(256) void prep(const float* __restrict__ x,
                                            const float* __restrict__ W1,
                                            const float* __restrict__ W2,
                                            bf16_t* __restrict__ xb,
                                            bf16_t* __restrict__ W1T,
                                            bf16_t* __restrict__ W2T,
                                            float* __restrict__ gmax) {
  int t = blockIdx.x * 256 + threadIdx.x;
  int stride = gridDim.x * 256;
  if (t == 0) *gmax = 0.f;
  for (int e = t; e < NROWS * KDIM / 4; e += stride) {
    f32x4 v = *(const f32x4*)(x + (size_t)e * 4);
    bf16x4 pk;
    pk[0] = (bf16_t)v[0]; pk[1] = (bf16_t)v[1];
    pk[2] = (bf16_t)v[2]; pk[3] = (bf16_t)v[3];
    *(bf16x4*)(xb + (size_t)e * 4) = pk;
  }
  for (int e = t; e < HID * KDIM; e += stride) {
    int n = e >> 9, k = e & 511;
    W1T[e] = (bf16_t)W1[k * HID + n];
  }
  for (int e = t; e < ODIM * HID; e += stride) {
    int n = e >> 8, k = e & 255;
    W2T[e] = (bf16_t)W2[k * ODIM + n];
  }
}

// ---------------------------------------------------------------------------
// gemm1: h1 = LeakyReLU(xb @ W1 + b1), bf16 out [16384][256]
// ---------------------------------------------------------------------------
__global__ __launch_bounds__(256) void gemm1(const bf16_t* __restrict__ xb,
                                             const bf16_t* __restrict__ W1T,
                                             const float* __restrict__ b1,
                                             bf16_t* __restrict__ h1) {
  __shared__ u16 As[128 * 40];
  __shared__ u16 Bs[64 * 40];
  int tid = threadIdx.x;
  int lane = tid & 63, w = tid >> 6;
  int r = lane & 15, q = lane >> 4;
  int wm = w & 1, wn = w >> 1;
  int mbase = blockIdx.x * 128, nbase = blockIdx.y * 64;

  f32x4 acc[4][2];
#pragma unroll
  for (int ms = 0; ms < 4; ms++)
#pragma unroll
    for (int ns = 0; ns < 2; ns++) acc[ms][ns] = (f32x4){0.f, 0.f, 0.f, 0.f};

  for (int kb = 0; kb < KDIM; kb += 32) {
#pragma unroll
    for (int i = 0; i < 2; i++) {
      int g = tid + 256 * i;
      int rr = g >> 2, c = (g & 3) * 8;
      *(bf16x8*)&As[rr * 40 + c] =
          *(const bf16x8*)(xb + (size_t)(mbase + rr) * KDIM + kb + c);
    }
    {
      int rr = tid >> 2, c = (tid & 3) * 8;
      *(bf16x8*)&Bs[rr * 40 + c] =
          *(const bf16x8*)(W1T + (size_t)(nbase + rr) * KDIM + kb + c);
    }
    __syncthreads();
    bf16x8 af[4], bfr[2];
#pragma unroll
    for (int ms = 0; ms < 4; ms++)
      af[ms] = *(bf16x8*)&As[(wm * 64 + ms * 16 + r) * 40 + q * 8];
#pragma unroll
    for (int ns = 0; ns < 2; ns++)
      bfr[ns] = *(bf16x8*)&Bs[(wn * 32 + ns * 16 + r) * 40 + q * 8];
#pragma unroll
    for (int ms = 0; ms < 4; ms++)
#pragma unroll
      for (int ns = 0; ns < 2; ns++)
        acc[ms][ns] = mfma16(af[ms], bfr[ns], acc[ms][ns]);
    __syncthreads();
  }
#pragma unroll
  for (int ns = 0; ns < 2; ns++) {
    int col = nbase + wn * 32 + ns * 16 + r;
    float bias = b1[col];
#pragma unroll
    for (int ms = 0; ms < 4; ms++) {
      int row0 = mbase + wm * 64 + ms * 16 + q * 4;
#pragma unroll
      for (int reg = 0; reg < 4; reg++) {
        float v = acc[ms][ns][reg] + bias;
        v = v >= 0.f ? v : 0.01f * v;
        h1[(size_t)(row0 + reg) * HID + col] = (bf16_t)v;
      }
    }
  }
}

// ---------------------------------------------------------------------------
// gemm2: h = h1 @ W2 + b2 -> hb bf16 [16384][128], hT bf16 [128][16384]
// ---------------------------------------------------------------------------
__global__ __launch_bounds__(256) void gemm2(const bf16_t* __restrict__ h1,
                                             const bf16_t* __restrict__ W2T,
                                             const float* __restrict__ b2,
                                             bf16_t* __restrict__ hb,
                                             bf16_t* __restrict__ hT) {
  __shared__ u16 As[128 * 40];
  __shared__ u16 Bs[64 * 40];
  int tid = threadIdx.x;
  int lane = tid & 63, w = tid >> 6;
  int r = lane & 15, q = lane >> 4;
  int wm = w & 1, wn = w >> 1;
  int mbase = blockIdx.x * 128, nbase = blockIdx.y * 64;

  f32x4 acc[4][2];
#pragma unroll
  for (int ms = 0; ms < 4; ms++)
#pragma unroll
    for (int ns = 0; ns < 2; ns++) acc[ms][ns] = (f32x4){0.f, 0.f, 0.f, 0.f};

  for (int kb = 0; kb < HID; kb += 32) {
#pragma unroll
    for (int i = 0; i < 2; i++) {
      int g = tid + 256 * i;
      int rr = g >> 2, c = (g & 3) * 8;
      *(bf16x8*)&As[rr * 40 + c] =
          *(const bf16x8*)(h1 + (size_t)(mbase + rr) * HID + kb + c);
    }
    {
      int rr = tid >> 2, c = (tid & 3) * 8;
      *(bf16x8*)&Bs[rr * 40 + c] =
          *(const bf16x8*)(W2T + (size_t)(nbase + rr) * HID + kb + c);
    }
    __syncthreads();
    bf16x8 af[4], bfr[2];
#pragma unroll
    for (int ms = 0; ms < 4; ms++)
      af[ms] = *(bf16x8*)&As[(wm * 64 + ms * 16 + r) * 40 + q * 8];
#pragma unroll
    for (int ns = 0; ns < 2; ns++)
      bfr[ns] = *(bf16x8*)&Bs[(wn * 32 + ns * 16 + r) * 40 + q * 8];
#pragma unroll
    for (int ms = 0; ms < 4; ms++)
#pragma unroll
      for (int ns = 0; ns < 2; ns++)
        acc[ms][ns] = mfma16(af[ms], bfr[ns], acc[ms][ns]);
    __syncthreads();
  }
#pragma unroll
  for (int ns = 0; ns < 2; ns++) {
    int col = nbase + wn * 32 + ns * 16 + r;
    float bias = b2[col];
#pragma unroll
    for (int ms = 0; ms < 4; ms++) {
      int row0 = mbase + wm * 64 + ms * 16 + q * 4;
      bf16x4 pk;
#pragma unroll
      for (int reg = 0; reg < 4; reg++) {
        float v = acc[ms][ns][reg] + bias;
        hb[(size_t)(row0 + reg) * ODIM + col] = (bf16_t)v;
        pk[reg] = (bf16_t)v;
      }
      *(bf16x4*)(hT + (size_t)col * NROWS + row0) = pk;
    }
  }
}

// ---------------------------------------------------------------------------
// rowstat: Mrow[i] = |h_i|^2 ; gmax = max_i |h_i|^2  (float-as-uint atomicMax)
// ---------------------------------------------------------------------------
__global__ __launch_bounds__(256) void rowstat(const bf16_t* __restrict__ hb,
                                               float* __restrict__ Mrow,
                                               float* __restrict__ gmax) {
  int row = blockIdx.x * 256 + threadIdx.x;
  const bf16x8* p = (const bf16x8*)(hb + (size_t)row * ODIM);
  float n2 = 0.f;
#pragma unroll
  for (int i = 0; i < 16; i++) {
    bf16x8 v = p[i];
#pragma unroll
    for (int j = 0; j < 8; j++) {
      float f = (float)v[j];
      n2 += f * f;
    }
  }
  Mrow[row] = n2;
  float m = n2;
#pragma unroll
  for (int off = 1; off < 64; off <<= 1) m = fmaxf(m, __shfl_xor(m, off, 64));
  if ((threadIdx.x & 63) == 0)
    atomicMax((unsigned int*)gmax, __float_as_uint(m));
}

// ---------------------------------------------------------------------------
// flash (split-K, fixed-shift softmax, 1 barrier/iter, full double-buffer):
// grid = 128 qtiles x KS. Block = 4 waves x 32 q-rows. m_i = |h_i|*maxnorm
// (Cauchy-Schwarz bound -> no online max, no rescale; l is per-lane partial).
// ---------------------------------------------------------------------------
__global__ __launch_bounds__(256, 4) void flash(const bf16_t* __restrict__ hb,
                                                const bf16_t* __restrict__ hT,
                                                const float* __restrict__ Mrow,
                                                const float* __restrict__ gmax,
                                                bf16_t* __restrict__ OpA,
                                                bf16_t* __restrict__ OpB,
                                                float* __restrict__ Ml) {
  __shared__ __align__(16) u16 KA[2][4096];  // 2 x 8KB [kr-frag blocks]
  __shared__ __align__(16) u16 KT[2][4096];  // 2 x 8KB [d-frag blocks]
  __shared__ __align__(16) u16 Pm[4096];     // 4 waves x 32 rows x 32 kr (XOR-swz)

  int tid = threadIdx.x;
  int lane = tid & 63, w = tid >> 6;
  int r = lane & 15, q = lane >> 4;
  int ksplit = blockIdx.x >> 7;
  int qtile = blockIdx.x & 127;
  int qbase = qtile * 128 + w * 32;
  int kbase = ksplit * (NROWS / KS);

  const char* gbase;
  size_t jmul;
  long ginc;
  u16 *d0, *d1;
  if (w < 2) {
    gbase = (const char*)(hb + (size_t)(kbase + w * 16 + r) * ODIM + q * 8);
    jmul = 64;                       // kk stride: 32 shorts
    ginc = 32 * ODIM * 2;            // next 32-k chunk
    d0 = &KA[0][w * 2048];
    d1 = &KA[1][w * 2048];
  } else {
    gbase = (const char*)(hT + (size_t)((w - 2) * 64 + r) * NROWS + kbase + q * 8);
    jmul = (size_t)16 * NROWS * 2;   // m8 stride: 16 d-rows
    ginc = 64;                       // next 32-k chunk
    d0 = &KT[0][(w - 2) * 2048];
    d1 = &KT[1][(w - 2) * 2048];
  }

  // Q fragments + fixed softmax shifts, resident in registers
  bf16x8 qf[2][4];
  float mi[2];
  float gm = gmax[0];
#pragma unroll
  for (int qt = 0; qt < 2; qt++) {
    int qrow = qbase + qt * 16 + r;
    mi[qt] = sqrtf(Mrow[qrow] * gm);
#pragma unroll
    for (int kk = 0; kk < 4; kk++)
      qf[qt][kk] = *(const bf16x8*)(hb + (size_t)qrow * ODIM + kk * 32 + q * 8);
  }

  f32x4 oa[8][2];
#pragma unroll
  for (int m8 = 0; m8 < 8; m8++)
#pragma unroll
    for (int qt = 0; qt < 2; qt++) oa[m8][qt] = (f32x4){0.f, 0.f, 0.f, 0.f};
  float lpart[2] = {0.f, 0.f};

  u16* pw = &Pm[w * 1024];
  int sw = (r & 3) * 8;  // XOR swizzle (8-short granules)

  // prologue: DMA iter 0 into buffer 0
#pragma unroll
  for (int j = 0; j < 4; j++) dma16(gbase + j * jmul, d0 + j * 512);
  gbase += ginc;

#define FLASH_ITER(BUF, PF)                                                   \
  {                                                                           \
    __syncthreads(); /* drains own DMAs; KA[BUF],KT[BUF] ready */             \
    if (PF) {                                                                 \
      u16* dd = (BUF) ? d0 : d1;                                              \
      _Pragma("unroll") for (int j = 0; j < 4; j++)                           \
          dma16(gbase + j * jmul, dd + j * 512);                              \
      gbase += ginc;                                                          \
    }                                                                         \
    f32x4 s[2][2];                                                            \
    _Pragma("unroll") for (int mt = 0; mt < 2; mt++)                          \
        _Pragma("unroll") for (int qt = 0; qt < 2; qt++)                      \
            s[mt][qt] = (f32x4){0.f, 0.f, 0.f, 0.f};                          \
    _Pragma("unroll") for (int mt = 0; mt < 2; mt++)                          \
        _Pragma("unroll") for (int kk = 0; kk < 4; kk++) {                    \
      bf16x8 af = *(bf16x8*)&KA[BUF][(mt * 4 + kk) * 512 + lane * 8];         \
      s[mt][0] = mfma16(af, qf[0][kk], s[mt][0]);                             \
      s[mt][1] = mfma16(af, qf[1][kk], s[mt][1]);                             \
    }                                                                         \
    _Pragma("unroll") for (int qt = 0; qt < 2; qt++) {                        \
      bf16x4 pk[2];                                                           \
      float rsum = 0.f;                                                       \
      _Pragma("unroll") for (int mt = 0; mt < 2; mt++)                        \
          _Pragma("unroll") for (int reg = 0; reg < 4; reg++) {               \
        float v = s[mt][qt][reg];                                             \
        float p = v > 0.f ? __expf(v - mi[qt]) : 0.f;                         \
        rsum += p;                                                            \
        pk[mt][reg] = (bf16_t)p;                                              \
      }                                                                       \
      lpart[qt] += rsum;                                                      \
      _Pragma("unroll") for (int mt = 0; mt < 2; mt++)                        \
        *(bf16x4*)&pw[(qt * 16 + r) * 32 +                                    \
                      (((mt * 16 + (q >> 1) * 8) ^ sw) + (q & 1) * 4)] =      \
            pk[mt];                                                           \
    }                                                                         \
    bf16x8 pf0 = *(bf16x8*)&pw[r * 32 + ((q * 8) ^ sw)];                      \
    bf16x8 pf1 = *(bf16x8*)&pw[(16 + r) * 32 + ((q * 8) ^ sw)];               \
    _Pragma("unroll") for (int m8 = 0; m8 < 8; m8++) {                        \
      bf16x8 af = *(bf16x8*)&KT[BUF][m8 * 512 + lane * 8];                    \
      oa[m8][0] = mfma16(af, pf0, oa[m8][0]);                                 \
      oa[m8][1] = mfma16(af, pf1, oa[m8][1]);                                 \
    }                                                                         \
  }

#pragma unroll 1
  for (int it2 = 0; it2 < 32; it2++) {
    FLASH_ITER(0, true)
    FLASH_ITER(1, (it2 < 31))
  }
#undef FLASH_ITER

  // ---- write partials: Op[ksplit][row][d] bf16, Ml[ksplit][row] = l ----
  bf16_t* op = ksplit < 6 ? OpA + (size_t)ksplit * NROWS * ODIM
                          : OpB + (size_t)(ksplit - 6) * NROWS * ODIM;
#pragma unroll
  for (int qt = 0; qt < 2; qt++) {
    float l = lpart[qt];
    l += __shfl_xor(l, 16, 64);
    l += __shfl_xor(l, 32, 64);
    int row = qbase + qt * 16 + r;
#pragma unroll
    for (int m8 = 0; m8 < 8; m8++) {
      bf16x4 pk;
#pragma unroll
      for (int reg = 0; reg < 4; reg++) pk[reg] = (bf16_t)oa[m8][qt][reg];
      *(bf16x4*)(op + (size_t)row * ODIM + m8 * 16 + q * 4) = pk;
    }
    if (q == 0) Ml[ksplit * NROWS + row] = l;
  }
}

// ---------------------------------------------------------------------------
// merge: lt = sum l_k ; out = log_softmax(alpha/lt * sum O_k + beta*h)
// ---------------------------------------------------------------------------
__global__ __launch_bounds__(256) void merge_ls(const bf16_t* __restrict__ OpA,
                                                const bf16_t* __restrict__ OpB,
                                                const float* __restrict__ Ml,
                                                const bf16_t* __restrict__ hbf,
                                                const float* __restrict__ alpha_p,
                                                const float* __restrict__ beta_p,
                                                float* __restrict__ out) {
  int tid = threadIdx.x, lane = tid & 63, w = tid >> 6;
  float al = alpha_p[0], be = beta_p[0];
  for (int i = 0; i < 8; i++) {
    int row = blockIdx.x * 32 + w * 8 + i;
    float lt = 0.f;
#pragma unroll
    for (int ksp = 0; ksp < KS; ksp++) lt += Ml[ksp * NROWS + row];
    float inv = al / lt;
    int d0 = lane * 2;
    float a0 = 0.f, a1 = 0.f;
#pragma unroll
    for (int ksp = 0; ksp < KS; ksp++) {
      const bf16_t* op = ksp < 6 ? OpA + (size_t)ksp * NROWS * ODIM
                                 : OpB + (size_t)(ksp - 6) * NROWS * ODIM;
      bf16x2 v = *(const bf16x2*)(op + (size_t)row * ODIM + d0);
      a0 += (float)v[0];
      a1 += (float)v[1];
    }
    bf16x2 hv = *(const bf16x2*)(hbf + (size_t)row * ODIM + d0);
    float v0 = inv * a0 + be * (float)hv[0];
    float v1 = inv * a1 + be * (float)hv[1];
    float mxv = fmaxf(v0, v1);
#pragma unroll
    for (int off = 1; off < 64; off <<= 1) mxv = fmaxf(mxv, __shfl_xor(mxv, off, 64));
    float se = __expf(v0 - mxv) + __expf(v1 - mxv);
#pragma unroll
    for (int off = 1; off < 64; off <<= 1) se += __shfl_xor(se, off, 64);
    float lz = mxv + __logf(se);
    f32x2 st = {v0 - lz, v1 - lz};
    *(f32x2*)(out + (size_t)row * ODIM + d0) = st;
  }
}

// ---------------------------------------------------------------------------
extern "C" void kernel_launch(void* const* d_in, const int* in_sizes, int n_in,
                              void* d_out, int out_size, void* d_ws,
                              size_t ws_size, hipStream_t stream) {
  const float* x     = (const float*)d_in[0];
  const float* W1    = (const float*)d_in[2];
  const float* b1    = (const float*)d_in[3];
  const float* W2    = (const float*)d_in[4];
  const float* b2    = (const float*)d_in[5];
  const float* alpha = (const float*)d_in[6];
  const float* beta  = (const float*)d_in[7];

  char* ws = (char*)d_ws;
  // [0, 25493504): xb/W1T/W2T/h1 — dead during flash/merge, reused as OpA.
  bf16_t* xb   = (bf16_t*)(ws + 0);
  bf16_t* W1T  = (bf16_t*)(ws + 16777216);
  bf16_t* W2T  = (bf16_t*)(ws + 17039360);
  bf16_t* h1   = (bf16_t*)(ws + 17104896);   // ends 25493504
  bf16_t* hbf  = (bf16_t*)(ws + 25493504);   // 4MB
  bf16_t* hT   = (bf16_t*)(ws + 29687808);   // 4MB
  float*  Ml   = (float*)(ws + 33882112);    // 512KB
  float*  Mrow = (float*)(ws + 34406400);    // 64KB
  float*  gmax = (float*)(ws + 34471936);    // 4B
  bf16_t* OpB  = (bf16_t*)(ws + 34930688);   // 2 x 4MB -> total 43.3MB
  bf16_t* OpA  = (bf16_t*)(ws + 0);          // overlays xb/W1T/W2T/h1
  float* outp  = (float*)d_out;

  prep<<<1024, 256, 0, stream>>>(x, W1, W2, xb, W1T, W2T, gmax);
  gemm1<<<dim3(128, 4), 256, 0, stream>>>(xb, W1T, b1, h1);
  gemm2<<<dim3(128, 2), 256, 0, stream>>>(h1, W2T, b2, hbf, hT);
  rowstat<<<64, 256, 0, stream>>>(hbf, Mrow, gmax);
  flash<<<128 * KS, 256, 0, stream>>>(hbf, hT, Mrow, gmax, OpA, OpB, Ml);
  merge_ls<<<512, 256, 0, stream>>>(OpA, OpB, Ml, hbf, alpha, beta, outp);
}

// Round 5
// 388.715 us; speedup vs baseline: 1.5019x; 1.5019x over previous
//
#include <hip/hip_runtime.h>
#include <hip/hip_bf16.h>

typedef __bf16 bf16_t;
typedef __bf16 bf16x8 __attribute__((ext_vector_type(8)));
typedef __bf16 bf16x4 __attribute__((ext_vector_type(4)));
typedef __bf16 bf16x2 __attribute__((ext_vector_type(2)));
typedef float f32x4 __attribute__((ext_vector_type(4)));
typedef float f32x2 __attribute__((ext_vector_type(2)));
typedef unsigned short u16;

#define NROWS 16384
#define KDIM  512
#define HID   256
#define ODIM  128
#define KS    8

__device__ __forceinline__ f32x4 mfma16(bf16x8 a, bf16x8 b, f32x4 c) {
  return __builtin_amdgcn_mfma_f32_16x16x32_bf16(a, b, c, 0, 0, 0);
}

__device__ __forceinline__ void dma16(const void* g, void* l) {
  __builtin_amdgcn_global_load_lds(
      (const __attribute__((address_space(1))) unsigned int*)g,
      (__attribute__((address_space(3))) unsigned int*)l, 16, 0, 0);
}

// ---------------------------------------------------------------------------
// prep: x fp32 -> xb bf16 ; W1 -> W1T bf16 ; W2 -> W2T bf16 ; zero gmax
// ---------------------------------------------------------------------------
__global__ __launch_bounds__(256) void prep(const float* __restrict__ x,
                                            const float* __restrict__ W1,
                                            const float* __restrict__ W2,
                                            bf16_t* __restrict__ xb,
                                            bf16_t* __restrict__ W1T,
                                            bf16_t* __restrict__ W2T,
                                            float* __restrict__ gmax) {
  int t = blockIdx.x * 256 + threadIdx.x;
  int stride = gridDim.x * 256;
  if (t == 0) *gmax = 0.f;
  for (int e = t; e < NROWS * KDIM / 4; e += stride) {
    f32x4 v = *(const f32x4*)(x + (size_t)e * 4);
    bf16x4 pk;
    pk[0] = (bf16_t)v[0]; pk[1] = (bf16_t)v[1];
    pk[2] = (bf16_t)v[2]; pk[3] = (bf16_t)v[3];
    *(bf16x4*)(xb + (size_t)e * 4) = pk;
  }
  for (int e = t; e < HID * KDIM; e += stride) {
    int n = e >> 9, k = e & 511;
    W1T[e] = (bf16_t)W1[k * HID + n];
  }
  for (int e = t; e < ODIM * HID; e += stride) {
    int n = e >> 8, k = e & 255;
    W2T[e] = (bf16_t)W2[k * ODIM + n];
  }
}

// ---------------------------------------------------------------------------
// gemm1: h1 = LeakyReLU(xb @ W1 + b1), bf16 out [16384][256]
// ---------------------------------------------------------------------------
__global__ __launch_bounds__(256) void gemm1(const bf16_t* __restrict__ xb,
                                             const bf16_t* __restrict__ W1T,
                                             const float* __restrict__ b1,
                                             bf16_t* __restrict__ h1) {
  __shared__ u16 As[128 * 40];
  __shared__ u16 Bs[64 * 40];
  int tid = threadIdx.x;
  int lane = tid & 63, w = tid >> 6;
  int r = lane & 15, q = lane >> 4;
  int wm = w & 1, wn = w >> 1;
  int mbase = blockIdx.x * 128, nbase = blockIdx.y * 64;

  f32x4 acc[4][2];
#pragma unroll
  for (int ms = 0; ms < 4; ms++)
#pragma unroll
    for (int ns = 0; ns < 2; ns++) acc[ms][ns] = (f32x4){0.f, 0.f, 0.f, 0.f};

  for (int kb = 0; kb < KDIM; kb += 32) {
#pragma unroll
    for (int i = 0; i < 2; i++) {
      int g = tid + 256 * i;
      int rr = g >> 2, c = (g & 3) * 8;
      *(bf16x8*)&As[rr * 40 + c] =
          *(const bf16x8*)(xb + (size_t)(mbase + rr) * KDIM + kb + c);
    }
    {
      int rr = tid >> 2, c = (tid & 3) * 8;
      *(bf16x8*)&Bs[rr * 40 + c] =
          *(const bf16x8*)(W1T + (size_t)(nbase + rr) * KDIM + kb + c);
    }
    __syncthreads();
    bf16x8 af[4], bfr[2];
#pragma unroll
    for (int ms = 0; ms < 4; ms++)
      af[ms] = *(bf16x8*)&As[(wm * 64 + ms * 16 + r) * 40 + q * 8];
#pragma unroll
    for (int ns = 0; ns < 2; ns++)
      bfr[ns] = *(bf16x8*)&Bs[(wn * 32 + ns * 16 + r) * 40 + q * 8];
#pragma unroll
    for (int ms = 0; ms < 4; ms++)
#pragma unroll
      for (int ns = 0; ns < 2; ns++)
        acc[ms][ns] = mfma16(af[ms], bfr[ns], acc[ms][ns]);
    __syncthreads();
  }
#pragma unroll
  for (int ns = 0; ns < 2; ns++) {
    int col = nbase + wn * 32 + ns * 16 + r;
    float bias = b1[col];
#pragma unroll
    for (int ms = 0; ms < 4; ms++) {
      int row0 = mbase + wm * 64 + ms * 16 + q * 4;
#pragma unroll
      for (int reg = 0; reg < 4; reg++) {
        float v = acc[ms][ns][reg] + bias;
        v = v >= 0.f ? v : 0.01f * v;
        h1[(size_t)(row0 + reg) * HID + col] = (bf16_t)v;
      }
    }
  }
}

// ---------------------------------------------------------------------------
// gemm2: h = h1 @ W2 + b2 -> hb bf16 [16384][128], hT bf16 [128][16384]
// ---------------------------------------------------------------------------
__global__ __launch_bounds__(256) void gemm2(const bf16_t* __restrict__ h1,
                                             const bf16_t* __restrict__ W2T,
                                             const float* __restrict__ b2,
                                             bf16_t* __restrict__ hb,
                                             bf16_t* __restrict__ hT) {
  __shared__ u16 As[128 * 40];
  __shared__ u16 Bs[64 * 40];
  int tid = threadIdx.x;
  int lane = tid & 63, w = tid >> 6;
  int r = lane & 15, q = lane >> 4;
  int wm = w & 1, wn = w >> 1;
  int mbase = blockIdx.x * 128, nbase = blockIdx.y * 64;

  f32x4 acc[4][2];
#pragma unroll
  for (int ms = 0; ms < 4; ms++)
#pragma unroll
    for (int ns = 0; ns < 2; ns++) acc[ms][ns] = (f32x4){0.f, 0.f, 0.f, 0.f};

  for (int kb = 0; kb < HID; kb += 32) {
#pragma unroll
    for (int i = 0; i < 2; i++) {
      int g = tid + 256 * i;
      int rr = g >> 2, c = (g & 3) * 8;
      *(bf16x8*)&As[rr * 40 + c] =
          *(const bf16x8*)(h1 + (size_t)(mbase + rr) * HID + kb + c);
    }
    {
      int rr = tid >> 2, c = (tid & 3) * 8;
      *(bf16x8*)&Bs[rr * 40 + c] =
          *(const bf16x8*)(W2T + (size_t)(nbase + rr) * HID + kb + c);
    }
    __syncthreads();
    bf16x8 af[4], bfr[2];
#pragma unroll
    for (int ms = 0; ms < 4; ms++)
      af[ms] = *(bf16x8*)&As[(wm * 64 + ms * 16 + r) * 40 + q * 8];
#pragma unroll
    for (int ns = 0; ns < 2; ns++)
      bfr[ns] = *(bf16x8*)&Bs[(wn * 32 + ns * 16 + r) * 40 + q * 8];
#pragma unroll
    for (int ms = 0; ms < 4; ms++)
#pragma unroll
      for (int ns = 0; ns < 2; ns++)
        acc[ms][ns] = mfma16(af[ms], bfr[ns], acc[ms][ns]);
    __syncthreads();
  }
#pragma unroll
  for (int ns = 0; ns < 2; ns++) {
    int col = nbase + wn * 32 + ns * 16 + r;
    float bias = b2[col];
#pragma unroll
    for (int ms = 0; ms < 4; ms++) {
      int row0 = mbase + wm * 64 + ms * 16 + q * 4;
      bf16x4 pk;
#pragma unroll
      for (int reg = 0; reg < 4; reg++) {
        float v = acc[ms][ns][reg] + bias;
        hb[(size_t)(row0 + reg) * ODIM + col] = (bf16_t)v;
        pk[reg] = (bf16_t)v;
      }
      *(bf16x4*)(hT + (size_t)col * NROWS + row0) = pk;
    }
  }
}

// ---------------------------------------------------------------------------
// rowstat: Mrow[i] = |h_i|^2 ; gmax = max_i |h_i|^2  (float-as-uint atomicMax)
// ---------------------------------------------------------------------------
__global__ __launch_bounds__(256) void rowstat(const bf16_t* __restrict__ hb,
                                               float* __restrict__ Mrow,
                                               float* __restrict__ gmax) {
  int row = blockIdx.x * 256 + threadIdx.x;
  const bf16x8* p = (const bf16x8*)(hb + (size_t)row * ODIM);
  float n2 = 0.f;
#pragma unroll
  for (int i = 0; i < 16; i++) {
    bf16x8 v = p[i];
#pragma unroll
    for (int j = 0; j < 8; j++) {
      float f = (float)v[j];
      n2 += f * f;
    }
  }
  Mrow[row] = n2;
  float m = n2;
#pragma unroll
  for (int off = 1; off < 64; off <<= 1) m = fmaxf(m, __shfl_xor(m, off, 64));
  if ((threadIdx.x & 63) == 0)
    atomicMax((unsigned int*)gmax, __float_as_uint(m));
}

// ---------------------------------------------------------------------------
// flash (split-K): EXACT round-3 loop/memory structure (2 barriers, KA single-
// buffered, KT double-buffered — this cadence keeps cross-block L2 reuse hot;
// round-4's 1-barrier variant thrashed L2: FETCH 43->918MB). Only change vs
// round 3: fixed-shift softmax m_i = |h_i|*maxnorm (Cauchy-Schwarz bound) ->
// no shfl trees / rescale / branch in the loop; l accumulated per-lane.
// ---------------------------------------------------------------------------
__global__ __launch_bounds__(256, 4) void flash(const bf16_t* __restrict__ hb,
                                                const bf16_t* __restrict__ hT,
                                                const float* __restrict__ Mrow,
                                                const float* __restrict__ gmax,
                                                bf16_t* __restrict__ OpA,
                                                bf16_t* __restrict__ OpB,
                                                float* __restrict__ Ml) {
  __shared__ __align__(16) u16 KA[8 * 512];       // 8 frag blocks of 1KB
  __shared__ __align__(16) u16 KT[2][8 * 512];    // double-buffered
  __shared__ __align__(16) u16 Pm[4 * 32 * 40];   // per-wave P [qr][kr]

  int tid = threadIdx.x;
  int lane = tid & 63, w = tid >> 6;
  int r = lane & 15, q = lane >> 4;
  int ksplit = blockIdx.x >> 7;
  int qtile = blockIdx.x & 127;
  int qbase = qtile * 128 + w * 32;
  int kbase = ksplit * (NROWS / KS);
  const int niter = (NROWS / KS) / 32;  // 64

  // staging: waves 0,1 -> KA blocks (mt=w, kk=j); waves 2,3 -> KT blocks
  const char* gbase;
  size_t jmul;
  long ginc;
  u16* dbase;
  if (w < 2) {
    gbase = (const char*)(hb + (size_t)(kbase + w * 16 + r) * ODIM + q * 8);
    jmul = 64;                      // kk stride: 32 shorts
    ginc = 32 * ODIM * 2;           // next 32-k chunk
    dbase = KA + w * 2048;
  } else {
    gbase = (const char*)(hT + (size_t)((w - 2) * 64 + r) * NROWS + kbase + q * 8);
    jmul = (size_t)16 * NROWS * 2;  // m8 stride: 16 d-rows
    ginc = 64;                      // next 32-k chunk
    dbase = KT[0] + (w - 2) * 2048;
  }

  // Q fragments + fixed softmax shifts, resident in registers
  bf16x8 qf[2][4];
  float mi[2];
  float gm = gmax[0];
#pragma unroll
  for (int qt = 0; qt < 2; qt++) {
    int qrow = qbase + qt * 16 + r;
    mi[qt] = sqrtf(Mrow[qrow] * gm);
#pragma unroll
    for (int kk = 0; kk < 4; kk++)
      qf[qt][kk] = *(const bf16x8*)(hb + (size_t)qrow * ODIM + kk * 32 + q * 8);
  }

  f32x4 oa[8][2];
#pragma unroll
  for (int m8 = 0; m8 < 8; m8++)
#pragma unroll
    for (int qt = 0; qt < 2; qt++) oa[m8][qt] = (f32x4){0.f, 0.f, 0.f, 0.f};
  float lpart[2] = {0.f, 0.f};

  // prologue: issue iter-0 DMAs (KT -> buffer 0)
#pragma unroll
  for (int j = 0; j < 4; j++) dma16(gbase + j * jmul, dbase + j * 512);
  gbase += ginc;

  for (int it = 0; it < niter; it++) {
    __syncthreads();  // drains vmcnt -> KA(it), KT(it) ready

    // ---- S^T = K_chunk . Q^T ----
    f32x4 s[2][2];
#pragma unroll
    for (int mt = 0; mt < 2; mt++)
#pragma unroll
      for (int qt = 0; qt < 2; qt++) s[mt][qt] = (f32x4){0.f, 0.f, 0.f, 0.f};
#pragma unroll
    for (int mt = 0; mt < 2; mt++)
#pragma unroll
      for (int kk = 0; kk < 4; kk++) {
        bf16x8 af = *(bf16x8*)&KA[(mt * 4 + kk) * 512 + lane * 8];
        s[mt][0] = mfma16(af, qf[0][kk], s[mt][0]);
        s[mt][1] = mfma16(af, qf[1][kk], s[mt][1]);
      }
    __syncthreads();  // all waves done reading KA

    // ---- prefetch next chunk (KA single-buf now free; KT -> other buffer) ----
    if (it + 1 < niter) {
      u16* d = dbase;
      if (w >= 2) d += ((it + 1) & 1) * 4096;
#pragma unroll
      for (int j = 0; j < 4; j++) dma16(gbase + j * jmul, d + j * 512);
      gbase += ginc;
    }

    // ---- fixed-shift masked softmax (no shfl, no rescale, no branch) ----
#pragma unroll
    for (int qt = 0; qt < 2; qt++) {
      float rsum = 0.f;
      bf16x4 pk[2];
#pragma unroll
      for (int mt = 0; mt < 2; mt++)
#pragma unroll
        for (int reg = 0; reg < 4; reg++) {
          float v = s[mt][qt][reg];
          float p = v > 0.f ? __expf(v - mi[qt]) : 0.f;
          rsum += p;
          pk[mt][reg] = (bf16_t)p;
        }
      lpart[qt] += rsum;
#pragma unroll
      for (int mt = 0; mt < 2; mt++)
        *(bf16x4*)&Pm[w * 1280 + (qt * 16 + r) * 40 + mt * 16 + q * 4] = pk[mt];
    }

    // ---- O^T += K^T . P^T ----
    bf16x8 pf0 = *(bf16x8*)&Pm[w * 1280 + r * 40 + q * 8];
    bf16x8 pf1 = *(bf16x8*)&Pm[w * 1280 + (16 + r) * 40 + q * 8];
    const u16* kt = KT[it & 1];
#pragma unroll
    for (int m8 = 0; m8 < 8; m8++) {
      bf16x8 af = *(bf16x8*)&kt[m8 * 512 + lane * 8];
      oa[m8][0] = mfma16(af, pf0, oa[m8][0]);
      oa[m8][1] = mfma16(af, pf1, oa[m8][1]);
    }
  }

  // ---- write partials: Op[ksplit][row][d] bf16, Ml[ksplit][row] = l ----
  bf16_t* op = ksplit < 6 ? OpA + (size_t)ksplit * NROWS * ODIM
                          : OpB + (size_t)(ksplit - 6) * NROWS * ODIM;
#pragma unroll
  for (int qt = 0; qt < 2; qt++) {
    float l = lpart[qt];
    l += __shfl_xor(l, 16, 64);
    l += __shfl_xor(l, 32, 64);
    int row = qbase + qt * 16 + r;
#pragma unroll
    for (int m8 = 0; m8 < 8; m8++) {
      bf16x4 pk;
#pragma unroll
      for (int reg = 0; reg < 4; reg++) pk[reg] = (bf16_t)oa[m8][qt][reg];
      *(bf16x4*)(op + (size_t)row * ODIM + m8 * 16 + q * 4) = pk;
    }
    if (q == 0) Ml[ksplit * NROWS + row] = l;
  }
}

// ---------------------------------------------------------------------------
// merge: lt = sum l_k ; out = log_softmax(alpha/lt * sum O_k + beta*h)
// ---------------------------------------------------------------------------
__global__ __launch_bounds__(256) void merge_ls(const bf16_t* __restrict__ OpA,
                                                const bf16_t* __restrict__ OpB,
                                                const float* __restrict__ Ml,
                                                const bf16_t* __restrict__ hbf,
                                                const float* __restrict__ alpha_p,
                                                const float* __restrict__ beta_p,
                                                float* __restrict__ out) {
  int tid = threadIdx.x, lane = tid & 63, w = tid >> 6;
  float al = alpha_p[0], be = beta_p[0];
  for (int i = 0; i < 8; i++) {
    int row = blockIdx.x * 32 + w * 8 + i;
    float lt = 0.f;
#pragma unroll
    for (int ksp = 0; ksp < KS; ksp++) lt += Ml[ksp * NROWS + row];
    float inv = al / lt;
    int d0 = lane * 2;
    float a0 = 0.f, a1 = 0.f;
#pragma unroll
    for (int ksp = 0; ksp < KS; ksp++) {
      const bf16_t* op = ksp < 6 ? OpA + (size_t)ksp * NROWS * ODIM
                                 : OpB + (size_t)(ksp - 6) * NROWS * ODIM;
      bf16x2 v = *(const bf16x2*)(op + (size_t)row * ODIM + d0);
      a0 += (float)v[0];
      a1 += (float)v[1];
    }
    bf16x2 hv = *(const bf16x2*)(hbf + (size_t)row * ODIM + d0);
    float v0 = inv * a0 + be * (float)hv[0];
    float v1 = inv * a1 + be * (float)hv[1];
    float mxv = fmaxf(v0, v1);
#pragma unroll
    for (int off = 1; off < 64; off <<= 1) mxv = fmaxf(mxv, __shfl_xor(mxv, off, 64));
    float se = __expf(v0 - mxv) + __expf(v1 - mxv);
#pragma unroll
    for (int off = 1; off < 64; off <<= 1) se += __shfl_xor(se, off, 64);
    float lz = mxv + __logf(se);
    f32x2 st = {v0 - lz, v1 - lz};
    *(f32x2*)(out + (size_t)row * ODIM + d0) = st;
  }
}

// ---------------------------------------------------------------------------
extern "C" void kernel_launch(void* const* d_in, const int* in_sizes, int n_in,
                              void* d_out, int out_size, void* d_ws,
                              size_t ws_size, hipStream_t stream) {
  const float* x     = (const float*)d_in[0];
  const float* W1    = (const float*)d_in[2];
  const float* b1    = (const float*)d_in[3];
  const float* W2    = (const float*)d_in[4];
  const float* b2    = (const float*)d_in[5];
  const float* alpha = (const float*)d_in[6];
  const float* beta  = (const float*)d_in[7];

  char* ws = (char*)d_ws;
  // [0, 25493504): xb/W1T/W2T/h1 — dead during flash/merge, reused as OpA.
  bf16_t* xb   = (bf16_t*)(ws + 0);
  bf16_t* W1T  = (bf16_t*)(ws + 16777216);
  bf16_t* W2T  = (bf16_t*)(ws + 17039360);
  bf16_t* h1   = (bf16_t*)(ws + 17104896);   // ends 25493504
  bf16_t* hbf  = (bf16_t*)(ws + 25493504);   // 4MB
  bf16_t* hT   = (bf16_t*)(ws + 29687808);   // 4MB
  float*  Ml   = (float*)(ws + 33882112);    // 512KB
  float*  Mrow = (float*)(ws + 34406400);    // 64KB
  float*  gmax = (float*)(ws + 34471936);    // 4B
  bf16_t* OpB  = (bf16_t*)(ws + 34930688);   // 2 x 4MB -> total 43.3MB
  bf16_t* OpA  = (bf16_t*)(ws + 0);          // overlays xb/W1T/W2T/h1
  float* outp  = (float*)d_out;

  prep<<<1024, 256, 0, stream>>>(x, W1, W2, xb, W1T, W2T, gmax);
  gemm1<<<dim3(128, 4), 256, 0, stream>>>(xb, W1T, b1, h1);
  gemm2<<<dim3(128, 2), 256, 0, stream>>>(h1, W2T, b2, hbf, hT);
  rowstat<<<64, 256, 0, stream>>>(hbf, Mrow, gmax);
  flash<<<128 * KS, 256, 0, stream>>>(hbf, hT, Mrow, gmax, OpA, OpB, Ml);
  merge_ls<<<512, 256, 0, stream>>>(OpA, OpB, Ml, hbf, alpha, beta, outp);
}